// Round 15
// baseline (59.856 us; speedup 1.0000x reference)
//
#include <hip/hip_runtime.h>
#include <hip/hip_bf16.h>

// NeRF surrogate renderer, MI355X — round 15: T-split 2-kernel + packed relu.
// R14: grid (512 blocks) capped occupancy at 31% because a block owned all 128
// samples of its 64 rays. Split T: render blocks own 64 rays x 64 samples
// (half-ray), write a 12-float partial composite state per (ray,half) to d_ws;
// a tiny combine kernel merges halves (i = i0 + T0*i1, T = T0*T1).
// Grid 1024 blocks, LDS 28.7KB -> up to 5 blocks/CU. Relu via pk_max (f32x4).

typedef float  f32x4  __attribute__((ext_vector_type(4)));
typedef short  bf16x8 __attribute__((ext_vector_type(8)));
typedef unsigned int u32;

__device__ __forceinline__ float fast_rcp(float x){ return __builtin_amdgcn_rcpf(x); }
__device__ __forceinline__ float softplus_f(float x){
    float e = __expf(-fabsf(x));
    return fmaxf(x,0.f) + __logf(1.f+e);
}
__device__ __forceinline__ float sigmoid_f(float x){ return fast_rcp(1.f+__expf(-x)); }

// hot-path pack: round-half-up + byte-select (3 VALU ops) — proven R12-R14
__device__ __forceinline__ u32 pkrn(float lo, float hi){
    const u32 a = __float_as_uint(lo) + 0x8000u;
    const u32 b = __float_as_uint(hi) + 0x8000u;
    return __builtin_amdgcn_perm(b, a, 0x07060302u);
}
// exact RNE pack (cold paths)
__device__ __forceinline__ u32 bfr_hi(float f){
    u32 u = __float_as_uint(f);
    return (u + 0x7FFFu + ((u>>16)&1u)) & 0xFFFF0000u;
}
__device__ __forceinline__ u32 pkbf(float lo, float hi){
    return (bfr_hi(lo)>>16) | bfr_hi(hi);
}

// ---- prep: identical to R12-R14 (proven) ----
__global__ __launch_bounds__(256)
void nerf_prep_kernel(const float* __restrict__ W1, const float* __restrict__ b1,
                      const float* __restrict__ Wsig, const float* __restrict__ Wsig_d,
                      const float* __restrict__ Wc1, const float* __restrict__ bc1,
                      const float* __restrict__ Wc2, const float* __restrict__ Wc2_d,
                      u32* __restrict__ ws)
{
    const int q0 = threadIdx.x;
#pragma unroll
    for (int k = 0; k < 6; ++k) {
        const int q = q0 + k*256;
        u32 val = 0u;
        if (q < 1024) {
            const int ut = q>>8, rem = q&255, lane = rem>>2, dw = rem&3;
            const int g = lane>>4, m = lane&15;
            if (g == 0) {
                float w[8];
                if (ut < 2) { const int u = ut*16 + m;
                    w[0]=W1[u];  w[1]=W1[32+u];  w[2]=W1[64+u];  w[3]=b1[u];
                    w[4]=0.f;    w[5]=0.f;       w[6]=0.f;       w[7]=0.f;
                } else {        const int u = (ut-2)*16 + m;
                    w[0]=Wc1[u]; w[1]=Wc1[32+u]; w[2]=Wc1[64+u]; w[3]=bc1[u];
                    w[4]=Wc1[96+u]; w[5]=Wc1[128+u]; w[6]=Wc1[160+u]; w[7]=0.f;
                }
                val = pkbf(w[2*dw], w[2*dw+1]);
            }
        } else {
            const int q2 = q-1024, ch = q2>>8, rem = q2&255, lane = rem>>2, dw = rem&3;
            const int g = lane>>4, o = lane&15;
            float w[2];
#pragma unroll
            for (int e = 0; e < 2; ++e) {
                const int kk = 2*dw + e;
                const int h = kk>>2, rr = kk&3;
                const int u_local = h*16 + g*4 + rr;
                float v = 0.f;
                if (ch == 0) {
                    if (o == 0) v = Wsig[u_local];
                    else if (o == 1) v = Wsig_d[u_local];
                } else {
                    if (o >= 2 && o <= 4) v = Wc2[u_local*3 + (o-2)];
                    else if (o >= 5 && o <= 7) v = Wc2_d[u_local*3 + (o-5)];
                }
                w[e] = v;
            }
            val = pkbf(w[0], w[1]);
        }
        ws[q] = val;
    }
}

#define PSTR 8     // posBuf ray stride (dw)
#define SSTR 20    // stash ray stride (dw)
#define WSTR 1792  // per-wave LDS dwords
#define CSTR 52    // combine ray stride (dw)
#define PART_OFF 2048   // dword offset of partial states in d_ws

// ---- render: block = 4 waves = 64 rays x halfT samples; 2 blocks per ray ----
__global__ __launch_bounds__(256, 5)
void nerf_render_kernel(const float* __restrict__ rays_o,
                        const float* __restrict__ rays_d,
                        const u32*  __restrict__ wsm,
                        const int*  __restrict__ num_steps,
                        float* __restrict__ partials,
                        int N)
{
    __shared__ u32 smem[4 * WSTR];   // 28 672 B

    const int tid  = threadIdx.x;
    const int seg  = tid>>6, lane = tid&63;    // seg 0..3
    const int half = blockIdx.x & 1;
    const int ray  = (blockIdx.x >> 1)*64 + lane;
    const int rayc = (ray < N) ? ray : (N-1);
    const int T = num_steps[0];
    const int g = lane>>4, c = lane&15;

    u32*   posW   = smem + seg*WSTR;
    float* stashW = (float*)(smem + seg*WSTR + 64*PSTR);
    float* comb   = (float*)smem;    // aliased; used only after barrier

    // weight fragments (proven layout), pinned
    const uint4* wsv = (const uint4*)wsm;
    uint4 a1u0 = wsv[0*64 + lane];
    uint4 a1u1 = wsv[1*64 + lane];
    uint4 a1u2 = wsv[2*64 + lane];
    uint4 a1u3 = wsv[3*64 + lane];
    uint4 a2u0 = wsv[256 + 0*64 + lane];
    uint4 a2u1 = wsv[256 + 1*64 + lane];
    asm volatile("" : "+v"(a1u0.x), "+v"(a1u0.y), "+v"(a1u0.z), "+v"(a1u0.w),
                      "+v"(a1u1.x), "+v"(a1u1.y), "+v"(a1u1.z), "+v"(a1u1.w),
                      "+v"(a1u2.x), "+v"(a1u2.y), "+v"(a1u2.z), "+v"(a1u2.w));
    asm volatile("" : "+v"(a1u3.x), "+v"(a1u3.y), "+v"(a1u3.z), "+v"(a1u3.w),
                      "+v"(a2u0.x), "+v"(a2u0.y), "+v"(a2u0.z), "+v"(a2u0.w),
                      "+v"(a2u1.x), "+v"(a2u1.y), "+v"(a2u1.z), "+v"(a2u1.w));

    // own-ray setup
    const float ox = rays_o[rayc*3+0], oy = rays_o[rayc*3+1], oz = rays_o[rayc*3+2];
    const float rdx = rays_d[rayc*3+0], rdy = rays_d[rayc*3+1], rdz = rays_d[rayc*3+2];
    const float rn = rsqrtf(rdx*rdx + rdy*rdy + rdz*rdz);
    const float dx = rdx*rn, dy = rdy*rn, dz = rdz*rn;

    const float ix = 1.0f/dx, iy = 1.0f/dy, iz = 1.0f/dz;
    const float t1x = (-1.f-ox)*ix, t2x = (1.f-ox)*ix;
    const float t1y = (-1.f-oy)*iy, t2y = (1.f-oy)*iy;
    const float t1z = (-1.f-oz)*iz, t2z = (1.f-oz)*iz;
    float nearv = fmaxf(fmaxf(fminf(t1x,t2x), fminf(t1y,t2y)), fminf(t1z,t2z));
    float farv  = fminf(fminf(fmaxf(t1x,t2x), fmaxf(t1y,t2y)), fmaxf(t1z,t2z));
    nearv = fmaxf(nearv, 0.2f);
    farv  = fmaxf(farv, nearv + 1e-6f);

    const float span    = farv - nearv;
    const float stepz   = (T > 1) ? span/(float)(T-1) : 0.f;
    const float inv_tm1 = (T > 1) ? 1.f/(float)(T-1) : 0.f;
    const float last_dt = span/(float)T;

    const u32 dirw0 = pkbf(dx, dy);
    const u32 dirw1 = pkbf(dz, 0.f);

    // segment bounds: this block covers samples [half*halfT, (half+1)*halfT)
    const int halfT = (T + 1) >> 1;
    const int Sper  = (halfT + 3) >> 2;
    const int hEnd  = ((half + 1)*halfT < T) ? (half + 1)*halfT : T;
    const int segStart = half*halfT + seg*Sper;
    int segEnd = segStart + Sper;
    segEnd = (segEnd < hEnd) ? segEnd : hEnd;
    const int nch = (segEnd > segStart) ? ((segEnd - segStart + 1) >> 1) : 0;

    const int posOff = 4*c;
    const int stOff  = (c>>1)*SSTR + (c&1)*8 + g*4;

    float iA0=0.f,iA1=0.f,iA2=0.f,dAc=0.f,wsA=0.f,TAx=1.f;
    float iD0=0.f,iD1=0.f,iD2=0.f,dDc=0.f,wsD=0.f,TDx=1.f;
    const f32x4 z4 = {0.f,0.f,0.f,0.f};

    for (int cs = 0; cs < nch; ++cs) {
        const int t0 = segStart + cs*2;

        // phase A: own-ray B1 columns for 2 samples
#pragma unroll
        for (int i = 0; i < 2; ++i) {
            const float zv = fmaf(stepz, (float)(t0 + i), nearv);
            const float X = fminf(fmaxf(fmaf(dx, zv, ox), -1.f), 1.f);
            const float Y = fminf(fmaxf(fmaf(dy, zv, oy), -1.f), 1.f);
            const float Z = fminf(fmaxf(fmaf(dz, zv, oz), -1.f), 1.f);
            uint4 v;
            v.x = pkrn(X, Y);
            v.y = pkrn(Z, 1.0f);
            v.z = dirw0;
            v.w = dirw1;
            *(uint4*)&posW[lane*PSTR + i*4] = v;
        }

        // phase B: 8 MFMA tiles; relu via pk_max (elementwise_max on f32x4)
#define TILEB(TAU)                                                                \
        {                                                                         \
            const uint4 b1u = *(const uint4*)&posW[(TAU)*(8*PSTR) + posOff];      \
            const bf16x8 b1f = __builtin_bit_cast(bf16x8, b1u);                   \
            f32x4 acc10 = __builtin_amdgcn_mfma_f32_16x16x32_bf16(                \
                __builtin_bit_cast(bf16x8, a1u0), b1f, z4, 0,0,0);                \
            f32x4 acc11 = __builtin_amdgcn_mfma_f32_16x16x32_bf16(                \
                __builtin_bit_cast(bf16x8, a1u1), b1f, z4, 0,0,0);                \
            f32x4 acc12 = __builtin_amdgcn_mfma_f32_16x16x32_bf16(                \
                __builtin_bit_cast(bf16x8, a1u2), b1f, z4, 0,0,0);                \
            f32x4 acc13 = __builtin_amdgcn_mfma_f32_16x16x32_bf16(                \
                __builtin_bit_cast(bf16x8, a1u3), b1f, z4, 0,0,0);                \
            const f32x4 r0 = __builtin_elementwise_max(acc10, z4);                \
            const f32x4 r1 = __builtin_elementwise_max(acc11, z4);                \
            const f32x4 r2 = __builtin_elementwise_max(acc12, z4);                \
            const f32x4 r3 = __builtin_elementwise_max(acc13, z4);                \
            uint4 b2a, b2b;                                                       \
            b2a.x = pkrn(r0.x, r0.y);  b2a.y = pkrn(r0.z, r0.w);                  \
            b2a.z = pkrn(r1.x, r1.y);  b2a.w = pkrn(r1.z, r1.w);                  \
            b2b.x = pkrn(r2.x, r2.y);  b2b.y = pkrn(r2.z, r2.w);                  \
            b2b.z = pkrn(r3.x, r3.y);  b2b.w = pkrn(r3.z, r3.w);                  \
            f32x4 acc2 = __builtin_amdgcn_mfma_f32_16x16x32_bf16(                 \
                __builtin_bit_cast(bf16x8, a2u0), __builtin_bit_cast(bf16x8, b2a),\
                z4, 0, 0, 0);                                                     \
            acc2 = __builtin_amdgcn_mfma_f32_16x16x32_bf16(                       \
                __builtin_bit_cast(bf16x8, a2u1), __builtin_bit_cast(bf16x8, b2b),\
                acc2, 0, 0, 0);                                                   \
            if (g < 2) {                                                          \
                *(f32x4*)&stashW[(TAU)*(8*SSTR) + stOff] = acc2;                  \
            }                                                                     \
        }
        TILEB(0) TILEB(1) TILEB(2) TILEB(3)
        TILEB(4) TILEB(5) TILEB(6) TILEB(7)
#undef TILEB

        // phase C: composite own ray's 2 samples
#pragma unroll
        for (int t = 0; t < 2; ++t) {
            const int tg = t0 + t;
            if (tg < segEnd) {
                const f32x4 oA = *(const f32x4*)&stashW[lane*SSTR + t*8];
                const f32x4 oB = *(const f32x4*)&stashW[lane*SSTR + t*8 + 4];
                const float dneg = (tg < T-1) ? -stepz : -last_dt;
                const float z01  = (float)tg * inv_tm1;

                const float sigA = softplus_f(oA.x);
                const float qA = __expf(dneg*sigA);
                const float wA = TAx - TAx*qA; TAx *= qA;
                iA0 = fmaf(wA, sigmoid_f(oA.z), iA0);
                iA1 = fmaf(wA, sigmoid_f(oA.w), iA1);
                iA2 = fmaf(wA, sigmoid_f(oB.x), iA2);
                dAc = fmaf(wA, z01, dAc); wsA += wA;

                const float sigD = softplus_f(oA.y);
                const float qD = __expf(dneg*sigD);
                const float wD = TDx - TDx*qD; TDx *= qD;
                iD0 = fmaf(wD, sigmoid_f(oB.y), iD0);
                iD1 = fmaf(wD, sigmoid_f(oB.z), iD1);
                iD2 = fmaf(wD, sigmoid_f(oB.w), iD2);
                dDc = fmaf(wD, z01, dDc); wsD += wD;
            }
        }
    }

    // combine the 4 waves' segment states (comb aliases smem)
    __syncthreads();
    *(f32x4*)&comb[lane*CSTR + seg*12 + 0] = (f32x4){iA0, iA1, iA2, dAc};
    *(f32x4*)&comb[lane*CSTR + seg*12 + 4] = (f32x4){wsA, TAx, iD0, iD1};
    *(f32x4*)&comb[lane*CSTR + seg*12 + 8] = (f32x4){iD2, dDc, wsD, TDx};
    __syncthreads();

    if (seg == 0 && ray < N) {
        float tA = TAx, tD = TDx;
#pragma unroll
        for (int s = 1; s < 4; ++s) {
            const f32x4 v0 = *(const f32x4*)&comb[lane*CSTR + s*12 + 0];
            const f32x4 v1 = *(const f32x4*)&comb[lane*CSTR + s*12 + 4];
            const f32x4 v2 = *(const f32x4*)&comb[lane*CSTR + s*12 + 8];
            iA0 = fmaf(tA, v0.x, iA0);
            iA1 = fmaf(tA, v0.y, iA1);
            iA2 = fmaf(tA, v0.z, iA2);
            dAc = fmaf(tA, v0.w, dAc);
            wsA = fmaf(tA, v1.x, wsA);
            tA *= v1.y;
            iD0 = fmaf(tD, v1.z, iD0);
            iD1 = fmaf(tD, v1.w, iD1);
            iD2 = fmaf(tD, v2.x, iD2);
            dDc = fmaf(tD, v2.y, dDc);
            wsD = fmaf(tD, v2.z, wsD);
            tD *= v2.w;
        }
        // write partial state for (ray, half)
        float* pw = partials + (size_t)(half*N + ray)*12;
        *(f32x4*)&pw[0] = (f32x4){iA0, iA1, iA2, dAc};
        *(f32x4*)&pw[4] = (f32x4){wsA, tA, iD0, iD1};
        *(f32x4*)&pw[8] = (f32x4){iD2, dDc, wsD, tD};
    }
}

// ---- combine: one lane per ray, merge the two halves ----
__global__ __launch_bounds__(256)
void nerf_combine_kernel(const float* __restrict__ partials,
                         float* __restrict__ out, int N)
{
    const int ray = blockIdx.x*256 + threadIdx.x;
    if (ray >= N) return;
    const float* p0 = partials + (size_t)ray*12;
    const float* p1 = partials + (size_t)(N + ray)*12;
    const f32x4 a0 = *(const f32x4*)&p0[0];
    const f32x4 a1 = *(const f32x4*)&p0[4];
    const f32x4 a2 = *(const f32x4*)&p0[8];
    const f32x4 b0 = *(const f32x4*)&p1[0];
    const f32x4 b1 = *(const f32x4*)&p1[4];
    const f32x4 b2 = *(const f32x4*)&p1[8];

    const float TA0 = a1.y, TD0 = a2.w;
    const float iA0 = a0.x + TA0*b0.x;
    const float iA1 = a0.y + TA0*b0.y;
    const float iA2 = a0.z + TA0*b0.z;
    const float dAc = a0.w + TA0*b0.w;
    const float wsA = a1.x + TA0*b1.x;
    const float iD0 = a1.z + TD0*b1.z;
    const float iD1 = a1.w + TD0*b1.w;
    const float iD2 = a2.x + TD0*b2.x;
    const float dDc = a2.y + TD0*b2.y;
    const float wsD = a2.z + TD0*b2.z;

    const float bgA = 1.f - wsA;
    const float bgD = 1.f - wsD;
    float* o = out + (size_t)ray * 9;
    o[0] = iA0 + bgA;
    o[1] = iA1 + bgA;
    o[2] = iA2 + bgA;
    o[3] = dAc;
    o[4] = wsA;
    o[5] = iD0 + bgD;
    o[6] = iD1 + bgD;
    o[7] = iD2 + bgD;
    o[8] = dDc;
}

extern "C" void kernel_launch(void* const* d_in, const int* in_sizes, int n_in,
                              void* d_out, int out_size, void* d_ws, size_t ws_size,
                              hipStream_t stream) {
    const float* rays_o = (const float*)d_in[0];
    const float* rays_d = (const float*)d_in[1];
    const float* W1     = (const float*)d_in[2];
    const float* b1     = (const float*)d_in[3];
    const float* Wsig   = (const float*)d_in[4];
    const float* Wsig_d = (const float*)d_in[5];
    const float* Wc1    = (const float*)d_in[6];
    const float* bc1    = (const float*)d_in[7];
    const float* Wc2    = (const float*)d_in[8];
    const float* Wc2_d  = (const float*)d_in[9];
    const int* num_steps = (const int*)d_in[10];

    const int N = in_sizes[0] / 3;
    float* out = (float*)d_out;
    u32*   ws  = (u32*)d_ws;
    float* partials = (float*)((u32*)d_ws + PART_OFF);  // 2*N*12 floats

    hipLaunchKernelGGL(nerf_prep_kernel, dim3(1), dim3(256), 0, stream,
                       W1, b1, Wsig, Wsig_d, Wc1, bc1, Wc2, Wc2_d, ws);

    const int rblocks = ((N + 63) / 64) * 2;   // 64 rays x half-T per block
    hipLaunchKernelGGL(nerf_render_kernel, dim3(rblocks), dim3(256), 0, stream,
                       rays_o, rays_d, ws, num_steps, partials, N);

    const int cblocks = (N + 255) / 256;
    hipLaunchKernelGGL(nerf_combine_kernel, dim3(cblocks), dim3(256), 0, stream,
                       partials, out, N);
}

// Round 16
// 50.966 us; speedup vs baseline: 1.1744x; 1.1744x over previous
//
#include <hip/hip_runtime.h>
#include <hip/hip_bf16.h>

// NeRF surrogate renderer, MI355X — round 16: consolidated best.
// R15 lesson: T-split didn't change total waves (occupancy unchanged) and the
// combine kernel cost 3us -> revert to R14 single-kernel (8 waves x 16 samples).
// Keep R15's proven pk_max relu; NEW: phase-B packs use 1-op truncation
// v_perm_b32 (relu'd >=0 values; <=0.4% rel err into GEMM2, tol is 2%).

typedef float  f32x4  __attribute__((ext_vector_type(4)));
typedef short  bf16x8 __attribute__((ext_vector_type(8)));
typedef unsigned int u32;

__device__ __forceinline__ float fast_rcp(float x){ return __builtin_amdgcn_rcpf(x); }
__device__ __forceinline__ float softplus_f(float x){
    float e = __expf(-fabsf(x));
    return fmaxf(x,0.f) + __logf(1.f+e);
}
__device__ __forceinline__ float sigmoid_f(float x){ return fast_rcp(1.f+__expf(-x)); }

// rounded pack (3 ops) — used in phase A (positions)
__device__ __forceinline__ u32 pkrn(float lo, float hi){
    const u32 a = __float_as_uint(lo) + 0x8000u;
    const u32 b = __float_as_uint(hi) + 0x8000u;
    return __builtin_amdgcn_perm(b, a, 0x07060302u);
}
// truncation pack (1 op) — phase B (relu'd trunk values, >=0)
__device__ __forceinline__ u32 pktr(float lo, float hi){
    return __builtin_amdgcn_perm(__float_as_uint(hi), __float_as_uint(lo), 0x07060302u);
}
// exact RNE pack (cold paths)
__device__ __forceinline__ u32 bfr_hi(float f){
    u32 u = __float_as_uint(f);
    return (u + 0x7FFFu + ((u>>16)&1u)) & 0xFFFF0000u;
}
__device__ __forceinline__ u32 pkbf(float lo, float hi){
    return (bfr_hi(lo)>>16) | bfr_hi(hi);
}

// ---- prep: identical to R12-R15 (proven) ----
__global__ __launch_bounds__(256)
void nerf_prep_kernel(const float* __restrict__ W1, const float* __restrict__ b1,
                      const float* __restrict__ Wsig, const float* __restrict__ Wsig_d,
                      const float* __restrict__ Wc1, const float* __restrict__ bc1,
                      const float* __restrict__ Wc2, const float* __restrict__ Wc2_d,
                      u32* __restrict__ ws)
{
    const int q0 = threadIdx.x;
#pragma unroll
    for (int k = 0; k < 6; ++k) {
        const int q = q0 + k*256;
        u32 val = 0u;
        if (q < 1024) {
            const int ut = q>>8, rem = q&255, lane = rem>>2, dw = rem&3;
            const int g = lane>>4, m = lane&15;
            if (g == 0) {
                float w[8];
                if (ut < 2) { const int u = ut*16 + m;
                    w[0]=W1[u];  w[1]=W1[32+u];  w[2]=W1[64+u];  w[3]=b1[u];
                    w[4]=0.f;    w[5]=0.f;       w[6]=0.f;       w[7]=0.f;
                } else {        const int u = (ut-2)*16 + m;
                    w[0]=Wc1[u]; w[1]=Wc1[32+u]; w[2]=Wc1[64+u]; w[3]=bc1[u];
                    w[4]=Wc1[96+u]; w[5]=Wc1[128+u]; w[6]=Wc1[160+u]; w[7]=0.f;
                }
                val = pkbf(w[2*dw], w[2*dw+1]);
            }
        } else {
            const int q2 = q-1024, ch = q2>>8, rem = q2&255, lane = rem>>2, dw = rem&3;
            const int g = lane>>4, o = lane&15;
            float w[2];
#pragma unroll
            for (int e = 0; e < 2; ++e) {
                const int kk = 2*dw + e;
                const int h = kk>>2, rr = kk&3;
                const int u_local = h*16 + g*4 + rr;
                float v = 0.f;
                if (ch == 0) {
                    if (o == 0) v = Wsig[u_local];
                    else if (o == 1) v = Wsig_d[u_local];
                } else {
                    if (o >= 2 && o <= 4) v = Wc2[u_local*3 + (o-2)];
                    else if (o >= 5 && o <= 7) v = Wc2_d[u_local*3 + (o-5)];
                }
                w[e] = v;
            }
            val = pkbf(w[0], w[1]);
        }
        ws[q] = val;
    }
}

#define PSTR 8     // posBuf ray stride (dw)
#define SSTR 20    // stash ray stride (dw)
#define WSTR 1792  // per-wave LDS dwords
#define CSTR 100   // combine ray stride (dw)

// ---- main: block = 8 waves = 64 rays x T samples (wave w = segment w) ----
__global__ __launch_bounds__(512, 4)
void nerf_render_kernel(const float* __restrict__ rays_o,
                        const float* __restrict__ rays_d,
                        const u32*  __restrict__ wsm,
                        const int*  __restrict__ num_steps,
                        float* __restrict__ out,
                        int N)
{
    __shared__ u32 smem[8 * WSTR];   // 57 344 B

    const int tid  = threadIdx.x;
    const int seg  = tid>>6, lane = tid&63;    // seg 0..7
    const int ray  = blockIdx.x*64 + lane;
    const int rayc = (ray < N) ? ray : (N-1);
    const int T = num_steps[0];
    const int g = lane>>4, c = lane&15;

    u32*   posW   = smem + seg*WSTR;
    float* stashW = (float*)(smem + seg*WSTR + 64*PSTR);
    float* comb   = (float*)smem;    // aliased; used only after barrier

    // weight fragments (proven layout), pinned
    const uint4* wsv = (const uint4*)wsm;
    uint4 a1u0 = wsv[0*64 + lane];
    uint4 a1u1 = wsv[1*64 + lane];
    uint4 a1u2 = wsv[2*64 + lane];
    uint4 a1u3 = wsv[3*64 + lane];
    uint4 a2u0 = wsv[256 + 0*64 + lane];
    uint4 a2u1 = wsv[256 + 1*64 + lane];
    asm volatile("" : "+v"(a1u0.x), "+v"(a1u0.y), "+v"(a1u0.z), "+v"(a1u0.w),
                      "+v"(a1u1.x), "+v"(a1u1.y), "+v"(a1u1.z), "+v"(a1u1.w),
                      "+v"(a1u2.x), "+v"(a1u2.y), "+v"(a1u2.z), "+v"(a1u2.w));
    asm volatile("" : "+v"(a1u3.x), "+v"(a1u3.y), "+v"(a1u3.z), "+v"(a1u3.w),
                      "+v"(a2u0.x), "+v"(a2u0.y), "+v"(a2u0.z), "+v"(a2u0.w),
                      "+v"(a2u1.x), "+v"(a2u1.y), "+v"(a2u1.z), "+v"(a2u1.w));

    // own-ray setup
    const float ox = rays_o[rayc*3+0], oy = rays_o[rayc*3+1], oz = rays_o[rayc*3+2];
    const float rdx = rays_d[rayc*3+0], rdy = rays_d[rayc*3+1], rdz = rays_d[rayc*3+2];
    const float rn = rsqrtf(rdx*rdx + rdy*rdy + rdz*rdz);
    const float dx = rdx*rn, dy = rdy*rn, dz = rdz*rn;

    const float ix = 1.0f/dx, iy = 1.0f/dy, iz = 1.0f/dz;
    const float t1x = (-1.f-ox)*ix, t2x = (1.f-ox)*ix;
    const float t1y = (-1.f-oy)*iy, t2y = (1.f-oy)*iy;
    const float t1z = (-1.f-oz)*iz, t2z = (1.f-oz)*iz;
    float nearv = fmaxf(fmaxf(fminf(t1x,t2x), fminf(t1y,t2y)), fminf(t1z,t2z));
    float farv  = fminf(fminf(fmaxf(t1x,t2x), fmaxf(t1y,t2y)), fmaxf(t1z,t2z));
    nearv = fmaxf(nearv, 0.2f);
    farv  = fmaxf(farv, nearv + 1e-6f);

    const float span    = farv - nearv;
    const float stepz   = (T > 1) ? span/(float)(T-1) : 0.f;
    const float inv_tm1 = (T > 1) ? 1.f/(float)(T-1) : 0.f;
    const float last_dt = span/(float)T;

    const u32 dirw0 = pkbf(dx, dy);
    const u32 dirw1 = pkbf(dz, 0.f);

    // segment bounds for this wave (8 segments)
    const int Sper = (T + 7) >> 3;
    const int segStart = seg * Sper;
    const int segEnd = (segStart + Sper < T) ? (segStart + Sper) : T;
    const int nch = (segEnd > segStart) ? ((segEnd - segStart + 1) >> 1) : 0;

    // per-lane constant LDS offsets (dwords)
    const int posOff = 4*c;
    const int stOff  = (c>>1)*SSTR + (c&1)*8 + g*4;

    // composite state (lane = ray)
    float iA0=0.f,iA1=0.f,iA2=0.f,dAc=0.f,wsA=0.f,TAx=1.f;
    float iD0=0.f,iD1=0.f,iD2=0.f,dDc=0.f,wsD=0.f,TDx=1.f;
    const f32x4 z4 = {0.f,0.f,0.f,0.f};

    for (int cs = 0; cs < nch; ++cs) {
        const int t0 = segStart + cs*2;

        // ---- phase A: own-ray B1 columns for 2 samples -> posBuf ----
#pragma unroll
        for (int i = 0; i < 2; ++i) {
            const float zv = fmaf(stepz, (float)(t0 + i), nearv);
            const float X = fminf(fmaxf(fmaf(dx, zv, ox), -1.f), 1.f);
            const float Y = fminf(fmaxf(fmaf(dy, zv, oy), -1.f), 1.f);
            const float Z = fminf(fmaxf(fmaf(dz, zv, oz), -1.f), 1.f);
            uint4 v;
            v.x = pkrn(X, Y);
            v.y = pkrn(Z, 1.0f);
            v.z = dirw0;
            v.w = dirw1;
            *(uint4*)&posW[lane*PSTR + i*4] = v;
        }

        // ---- phase B: 8 MFMA tiles; pk_max relu + 1-op truncation packs ----
#define TILEB(TAU)                                                                \
        {                                                                         \
            const uint4 b1u = *(const uint4*)&posW[(TAU)*(8*PSTR) + posOff];      \
            const bf16x8 b1f = __builtin_bit_cast(bf16x8, b1u);                   \
            f32x4 acc10 = __builtin_amdgcn_mfma_f32_16x16x32_bf16(                \
                __builtin_bit_cast(bf16x8, a1u0), b1f, z4, 0,0,0);                \
            f32x4 acc11 = __builtin_amdgcn_mfma_f32_16x16x32_bf16(                \
                __builtin_bit_cast(bf16x8, a1u1), b1f, z4, 0,0,0);                \
            f32x4 acc12 = __builtin_amdgcn_mfma_f32_16x16x32_bf16(                \
                __builtin_bit_cast(bf16x8, a1u2), b1f, z4, 0,0,0);                \
            f32x4 acc13 = __builtin_amdgcn_mfma_f32_16x16x32_bf16(                \
                __builtin_bit_cast(bf16x8, a1u3), b1f, z4, 0,0,0);                \
            const f32x4 r0 = __builtin_elementwise_max(acc10, z4);                \
            const f32x4 r1 = __builtin_elementwise_max(acc11, z4);                \
            const f32x4 r2 = __builtin_elementwise_max(acc12, z4);                \
            const f32x4 r3 = __builtin_elementwise_max(acc13, z4);                \
            uint4 b2a, b2b;                                                       \
            b2a.x = pktr(r0.x, r0.y);  b2a.y = pktr(r0.z, r0.w);                  \
            b2a.z = pktr(r1.x, r1.y);  b2a.w = pktr(r1.z, r1.w);                  \
            b2b.x = pktr(r2.x, r2.y);  b2b.y = pktr(r2.z, r2.w);                  \
            b2b.z = pktr(r3.x, r3.y);  b2b.w = pktr(r3.z, r3.w);                  \
            f32x4 acc2 = __builtin_amdgcn_mfma_f32_16x16x32_bf16(                 \
                __builtin_bit_cast(bf16x8, a2u0), __builtin_bit_cast(bf16x8, b2a),\
                z4, 0, 0, 0);                                                     \
            acc2 = __builtin_amdgcn_mfma_f32_16x16x32_bf16(                       \
                __builtin_bit_cast(bf16x8, a2u1), __builtin_bit_cast(bf16x8, b2b),\
                acc2, 0, 0, 0);                                                   \
            if (g < 2) {                                                          \
                *(f32x4*)&stashW[(TAU)*(8*SSTR) + stOff] = acc2;                  \
            }                                                                     \
        }
        TILEB(0) TILEB(1) TILEB(2) TILEB(3)
        TILEB(4) TILEB(5) TILEB(6) TILEB(7)
#undef TILEB

        // ---- phase C: composite own ray's 2 samples (sequential, in-reg) ----
#pragma unroll
        for (int t = 0; t < 2; ++t) {
            const int tg = t0 + t;
            if (tg < segEnd) {
                const f32x4 oA = *(const f32x4*)&stashW[lane*SSTR + t*8];
                const f32x4 oB = *(const f32x4*)&stashW[lane*SSTR + t*8 + 4];
                const float dneg = (tg < T-1) ? -stepz : -last_dt;
                const float z01  = (float)tg * inv_tm1;

                const float sigA = softplus_f(oA.x);
                const float qA = __expf(dneg*sigA);
                const float wA = TAx - TAx*qA; TAx *= qA;
                iA0 = fmaf(wA, sigmoid_f(oA.z), iA0);
                iA1 = fmaf(wA, sigmoid_f(oA.w), iA1);
                iA2 = fmaf(wA, sigmoid_f(oB.x), iA2);
                dAc = fmaf(wA, z01, dAc); wsA += wA;

                const float sigD = softplus_f(oA.y);
                const float qD = __expf(dneg*sigD);
                const float wD = TDx - TDx*qD; TDx *= qD;
                iD0 = fmaf(wD, sigmoid_f(oB.y), iD0);
                iD1 = fmaf(wD, sigmoid_f(oB.z), iD1);
                iD2 = fmaf(wD, sigmoid_f(oB.w), iD2);
                dDc = fmaf(wD, z01, dDc); wsD += wD;
            }
        }
    }

    // ---- combine the 8 waves' segment states (comb aliases smem) ----
    __syncthreads();
    *(f32x4*)&comb[lane*CSTR + seg*12 + 0] = (f32x4){iA0, iA1, iA2, dAc};
    *(f32x4*)&comb[lane*CSTR + seg*12 + 4] = (f32x4){wsA, TAx, iD0, iD1};
    *(f32x4*)&comb[lane*CSTR + seg*12 + 8] = (f32x4){iD2, dDc, wsD, TDx};
    __syncthreads();

    if (seg == 0) {
        float tA = TAx, tD = TDx;
#pragma unroll
        for (int s = 1; s < 8; ++s) {
            const f32x4 v0 = *(const f32x4*)&comb[lane*CSTR + s*12 + 0];
            const f32x4 v1 = *(const f32x4*)&comb[lane*CSTR + s*12 + 4];
            const f32x4 v2 = *(const f32x4*)&comb[lane*CSTR + s*12 + 8];
            iA0 = fmaf(tA, v0.x, iA0);
            iA1 = fmaf(tA, v0.y, iA1);
            iA2 = fmaf(tA, v0.z, iA2);
            dAc = fmaf(tA, v0.w, dAc);
            wsA = fmaf(tA, v1.x, wsA);
            tA *= v1.y;
            iD0 = fmaf(tD, v1.z, iD0);
            iD1 = fmaf(tD, v1.w, iD1);
            iD2 = fmaf(tD, v2.x, iD2);
            dDc = fmaf(tD, v2.y, dDc);
            wsD = fmaf(tD, v2.z, wsD);
            tD *= v2.w;
        }
        if (ray < N) {
            const float bgA = 1.f - wsA;
            const float bgD = 1.f - wsD;
            float* o = out + (size_t)ray * 9;
            o[0] = iA0 + bgA;
            o[1] = iA1 + bgA;
            o[2] = iA2 + bgA;
            o[3] = dAc;
            o[4] = wsA;
            o[5] = iD0 + bgD;
            o[6] = iD1 + bgD;
            o[7] = iD2 + bgD;
            o[8] = dDc;
        }
    }
}

extern "C" void kernel_launch(void* const* d_in, const int* in_sizes, int n_in,
                              void* d_out, int out_size, void* d_ws, size_t ws_size,
                              hipStream_t stream) {
    const float* rays_o = (const float*)d_in[0];
    const float* rays_d = (const float*)d_in[1];
    const float* W1     = (const float*)d_in[2];
    const float* b1     = (const float*)d_in[3];
    const float* Wsig   = (const float*)d_in[4];
    const float* Wsig_d = (const float*)d_in[5];
    const float* Wc1    = (const float*)d_in[6];
    const float* bc1    = (const float*)d_in[7];
    const float* Wc2    = (const float*)d_in[8];
    const float* Wc2_d  = (const float*)d_in[9];
    const int* num_steps = (const int*)d_in[10];

    const int N = in_sizes[0] / 3;
    float* out = (float*)d_out;
    u32*   ws  = (u32*)d_ws;    // 6 KB used

    hipLaunchKernelGGL(nerf_prep_kernel, dim3(1), dim3(256), 0, stream,
                       W1, b1, Wsig, Wsig_d, Wc1, bc1, Wc2, Wc2_d, ws);

    const int blocks = (N + 63) / 64;   // 64 rays per block (8 waves)
    hipLaunchKernelGGL(nerf_render_kernel, dim3(blocks), dim3(512), 0, stream,
                       rays_o, rays_d, ws, num_steps, out, N);
}

// Round 17
// 50.594 us; speedup vs baseline: 1.1831x; 1.0074x over previous
//
#include <hip/hip_runtime.h>
#include <hip/hip_bf16.h>

// NeRF surrogate renderer, MI355X — round 17: final glue bundle.
// R16 (51.0us): phase C is now the largest VALU consumer. This round:
//  (1) phase-A packs -> 1-op truncation (positions; 5x absmax headroom)
//  (2) exp2 folding for alpha (pre-scaled -delta*log2e; saves __expf's mul)
//  (3) s_setprio(1) around phase-B MFMA cluster (independent-wave regime,
//      m191-positive; not the lockstep-GEMM null case)

typedef float  f32x4  __attribute__((ext_vector_type(4)));
typedef short  bf16x8 __attribute__((ext_vector_type(8)));
typedef unsigned int u32;

__device__ __forceinline__ float fast_rcp(float x){ return __builtin_amdgcn_rcpf(x); }
__device__ __forceinline__ float softplus_f(float x){
    float e = __expf(-fabsf(x));
    return fmaxf(x,0.f) + __logf(1.f+e);
}
__device__ __forceinline__ float sigmoid_f(float x){ return fast_rcp(1.f+__expf(-x)); }

// truncation pack (1 op): (bf16(hi)<<16)|bf16(lo), RTZ
__device__ __forceinline__ u32 pktr(float lo, float hi){
    return __builtin_amdgcn_perm(__float_as_uint(hi), __float_as_uint(lo), 0x07060302u);
}
// exact RNE pack (cold paths)
__device__ __forceinline__ u32 bfr_hi(float f){
    u32 u = __float_as_uint(f);
    return (u + 0x7FFFu + ((u>>16)&1u)) & 0xFFFF0000u;
}
__device__ __forceinline__ u32 pkbf(float lo, float hi){
    return (bfr_hi(lo)>>16) | bfr_hi(hi);
}

// ---- prep: identical to R12-R16 (proven) ----
__global__ __launch_bounds__(256)
void nerf_prep_kernel(const float* __restrict__ W1, const float* __restrict__ b1,
                      const float* __restrict__ Wsig, const float* __restrict__ Wsig_d,
                      const float* __restrict__ Wc1, const float* __restrict__ bc1,
                      const float* __restrict__ Wc2, const float* __restrict__ Wc2_d,
                      u32* __restrict__ ws)
{
    const int q0 = threadIdx.x;
#pragma unroll
    for (int k = 0; k < 6; ++k) {
        const int q = q0 + k*256;
        u32 val = 0u;
        if (q < 1024) {
            const int ut = q>>8, rem = q&255, lane = rem>>2, dw = rem&3;
            const int g = lane>>4, m = lane&15;
            if (g == 0) {
                float w[8];
                if (ut < 2) { const int u = ut*16 + m;
                    w[0]=W1[u];  w[1]=W1[32+u];  w[2]=W1[64+u];  w[3]=b1[u];
                    w[4]=0.f;    w[5]=0.f;       w[6]=0.f;       w[7]=0.f;
                } else {        const int u = (ut-2)*16 + m;
                    w[0]=Wc1[u]; w[1]=Wc1[32+u]; w[2]=Wc1[64+u]; w[3]=bc1[u];
                    w[4]=Wc1[96+u]; w[5]=Wc1[128+u]; w[6]=Wc1[160+u]; w[7]=0.f;
                }
                val = pkbf(w[2*dw], w[2*dw+1]);
            }
        } else {
            const int q2 = q-1024, ch = q2>>8, rem = q2&255, lane = rem>>2, dw = rem&3;
            const int g = lane>>4, o = lane&15;
            float w[2];
#pragma unroll
            for (int e = 0; e < 2; ++e) {
                const int kk = 2*dw + e;
                const int h = kk>>2, rr = kk&3;
                const int u_local = h*16 + g*4 + rr;
                float v = 0.f;
                if (ch == 0) {
                    if (o == 0) v = Wsig[u_local];
                    else if (o == 1) v = Wsig_d[u_local];
                } else {
                    if (o >= 2 && o <= 4) v = Wc2[u_local*3 + (o-2)];
                    else if (o >= 5 && o <= 7) v = Wc2_d[u_local*3 + (o-5)];
                }
                w[e] = v;
            }
            val = pkbf(w[0], w[1]);
        }
        ws[q] = val;
    }
}

#define PSTR 8     // posBuf ray stride (dw)
#define SSTR 20    // stash ray stride (dw)
#define WSTR 1792  // per-wave LDS dwords
#define CSTR 100   // combine ray stride (dw)
#define LOG2E 1.44269504088896340736f

// ---- main: block = 8 waves = 64 rays x T samples (wave w = segment w) ----
__global__ __launch_bounds__(512, 4)
void nerf_render_kernel(const float* __restrict__ rays_o,
                        const float* __restrict__ rays_d,
                        const u32*  __restrict__ wsm,
                        const int*  __restrict__ num_steps,
                        float* __restrict__ out,
                        int N)
{
    __shared__ u32 smem[8 * WSTR];   // 57 344 B

    const int tid  = threadIdx.x;
    const int seg  = tid>>6, lane = tid&63;    // seg 0..7
    const int ray  = blockIdx.x*64 + lane;
    const int rayc = (ray < N) ? ray : (N-1);
    const int T = num_steps[0];
    const int g = lane>>4, c = lane&15;

    u32*   posW   = smem + seg*WSTR;
    float* stashW = (float*)(smem + seg*WSTR + 64*PSTR);
    float* comb   = (float*)smem;    // aliased; used only after barrier

    // weight fragments (proven layout), pinned
    const uint4* wsv = (const uint4*)wsm;
    uint4 a1u0 = wsv[0*64 + lane];
    uint4 a1u1 = wsv[1*64 + lane];
    uint4 a1u2 = wsv[2*64 + lane];
    uint4 a1u3 = wsv[3*64 + lane];
    uint4 a2u0 = wsv[256 + 0*64 + lane];
    uint4 a2u1 = wsv[256 + 1*64 + lane];
    asm volatile("" : "+v"(a1u0.x), "+v"(a1u0.y), "+v"(a1u0.z), "+v"(a1u0.w),
                      "+v"(a1u1.x), "+v"(a1u1.y), "+v"(a1u1.z), "+v"(a1u1.w),
                      "+v"(a1u2.x), "+v"(a1u2.y), "+v"(a1u2.z), "+v"(a1u2.w));
    asm volatile("" : "+v"(a1u3.x), "+v"(a1u3.y), "+v"(a1u3.z), "+v"(a1u3.w),
                      "+v"(a2u0.x), "+v"(a2u0.y), "+v"(a2u0.z), "+v"(a2u0.w),
                      "+v"(a2u1.x), "+v"(a2u1.y), "+v"(a2u1.z), "+v"(a2u1.w));

    // own-ray setup
    const float ox = rays_o[rayc*3+0], oy = rays_o[rayc*3+1], oz = rays_o[rayc*3+2];
    const float rdx = rays_d[rayc*3+0], rdy = rays_d[rayc*3+1], rdz = rays_d[rayc*3+2];
    const float rn = rsqrtf(rdx*rdx + rdy*rdy + rdz*rdz);
    const float dx = rdx*rn, dy = rdy*rn, dz = rdz*rn;

    const float ix = 1.0f/dx, iy = 1.0f/dy, iz = 1.0f/dz;
    const float t1x = (-1.f-ox)*ix, t2x = (1.f-ox)*ix;
    const float t1y = (-1.f-oy)*iy, t2y = (1.f-oy)*iy;
    const float t1z = (-1.f-oz)*iz, t2z = (1.f-oz)*iz;
    float nearv = fmaxf(fmaxf(fminf(t1x,t2x), fminf(t1y,t2y)), fminf(t1z,t2z));
    float farv  = fminf(fminf(fmaxf(t1x,t2x), fmaxf(t1y,t2y)), fmaxf(t1z,t2z));
    nearv = fmaxf(nearv, 0.2f);
    farv  = fmaxf(farv, nearv + 1e-6f);

    const float span    = farv - nearv;
    const float stepz   = (T > 1) ? span/(float)(T-1) : 0.f;
    const float inv_tm1 = (T > 1) ? 1.f/(float)(T-1) : 0.f;
    const float last_dt = span/(float)T;
    const float nStep2  = -stepz  * LOG2E;   // pre-scaled for exp2f
    const float nLast2  = -last_dt * LOG2E;

    const u32 dirw0 = pkbf(dx, dy);
    const u32 dirw1 = pkbf(dz, 0.f);

    // segment bounds for this wave (8 segments)
    const int Sper = (T + 7) >> 3;
    const int segStart = seg * Sper;
    const int segEnd = (segStart + Sper < T) ? (segStart + Sper) : T;
    const int nch = (segEnd > segStart) ? ((segEnd - segStart + 1) >> 1) : 0;

    // per-lane constant LDS offsets (dwords)
    const int posOff = 4*c;
    const int stOff  = (c>>1)*SSTR + (c&1)*8 + g*4;

    // composite state (lane = ray)
    float iA0=0.f,iA1=0.f,iA2=0.f,dAc=0.f,wsA=0.f,TAx=1.f;
    float iD0=0.f,iD1=0.f,iD2=0.f,dDc=0.f,wsD=0.f,TDx=1.f;
    const f32x4 z4 = {0.f,0.f,0.f,0.f};

    for (int cs = 0; cs < nch; ++cs) {
        const int t0 = segStart + cs*2;

        // ---- phase A: own-ray B1 columns for 2 samples -> posBuf ----
#pragma unroll
        for (int i = 0; i < 2; ++i) {
            const float zv = fmaf(stepz, (float)(t0 + i), nearv);
            const float X = fminf(fmaxf(fmaf(dx, zv, ox), -1.f), 1.f);
            const float Y = fminf(fmaxf(fmaf(dy, zv, oy), -1.f), 1.f);
            const float Z = fminf(fmaxf(fmaf(dz, zv, oz), -1.f), 1.f);
            uint4 v;
            v.x = pktr(X, Y);
            v.y = pktr(Z, 1.0f);
            v.z = dirw0;
            v.w = dirw1;
            *(uint4*)&posW[lane*PSTR + i*4] = v;
        }

        // ---- phase B: 8 MFMA tiles (setprio-boosted); pk_max relu + trunc packs ----
        __builtin_amdgcn_s_setprio(1);
#define TILEB(TAU)                                                                \
        {                                                                         \
            const uint4 b1u = *(const uint4*)&posW[(TAU)*(8*PSTR) + posOff];      \
            const bf16x8 b1f = __builtin_bit_cast(bf16x8, b1u);                   \
            f32x4 acc10 = __builtin_amdgcn_mfma_f32_16x16x32_bf16(                \
                __builtin_bit_cast(bf16x8, a1u0), b1f, z4, 0,0,0);                \
            f32x4 acc11 = __builtin_amdgcn_mfma_f32_16x16x32_bf16(                \
                __builtin_bit_cast(bf16x8, a1u1), b1f, z4, 0,0,0);                \
            f32x4 acc12 = __builtin_amdgcn_mfma_f32_16x16x32_bf16(                \
                __builtin_bit_cast(bf16x8, a1u2), b1f, z4, 0,0,0);                \
            f32x4 acc13 = __builtin_amdgcn_mfma_f32_16x16x32_bf16(                \
                __builtin_bit_cast(bf16x8, a1u3), b1f, z4, 0,0,0);                \
            const f32x4 r0 = __builtin_elementwise_max(acc10, z4);                \
            const f32x4 r1 = __builtin_elementwise_max(acc11, z4);                \
            const f32x4 r2 = __builtin_elementwise_max(acc12, z4);                \
            const f32x4 r3 = __builtin_elementwise_max(acc13, z4);                \
            uint4 b2a, b2b;                                                       \
            b2a.x = pktr(r0.x, r0.y);  b2a.y = pktr(r0.z, r0.w);                  \
            b2a.z = pktr(r1.x, r1.y);  b2a.w = pktr(r1.z, r1.w);                  \
            b2b.x = pktr(r2.x, r2.y);  b2b.y = pktr(r2.z, r2.w);                  \
            b2b.z = pktr(r3.x, r3.y);  b2b.w = pktr(r3.z, r3.w);                  \
            f32x4 acc2 = __builtin_amdgcn_mfma_f32_16x16x32_bf16(                 \
                __builtin_bit_cast(bf16x8, a2u0), __builtin_bit_cast(bf16x8, b2a),\
                z4, 0, 0, 0);                                                     \
            acc2 = __builtin_amdgcn_mfma_f32_16x16x32_bf16(                       \
                __builtin_bit_cast(bf16x8, a2u1), __builtin_bit_cast(bf16x8, b2b),\
                acc2, 0, 0, 0);                                                   \
            if (g < 2) {                                                          \
                *(f32x4*)&stashW[(TAU)*(8*SSTR) + stOff] = acc2;                  \
            }                                                                     \
        }
        TILEB(0) TILEB(1) TILEB(2) TILEB(3)
        TILEB(4) TILEB(5) TILEB(6) TILEB(7)
#undef TILEB
        __builtin_amdgcn_s_setprio(0);

        // ---- phase C: composite own ray's 2 samples (sequential, in-reg) ----
#pragma unroll
        for (int t = 0; t < 2; ++t) {
            const int tg = t0 + t;
            if (tg < segEnd) {
                const f32x4 oA = *(const f32x4*)&stashW[lane*SSTR + t*8];
                const f32x4 oB = *(const f32x4*)&stashW[lane*SSTR + t*8 + 4];
                const float dneg2 = (tg < T-1) ? nStep2 : nLast2;
                const float z01   = (float)tg * inv_tm1;

                const float sigA = softplus_f(oA.x);
                const float qA = exp2f(dneg2*sigA);
                const float wA = TAx - TAx*qA; TAx *= qA;
                iA0 = fmaf(wA, sigmoid_f(oA.z), iA0);
                iA1 = fmaf(wA, sigmoid_f(oA.w), iA1);
                iA2 = fmaf(wA, sigmoid_f(oB.x), iA2);
                dAc = fmaf(wA, z01, dAc); wsA += wA;

                const float sigD = softplus_f(oA.y);
                const float qD = exp2f(dneg2*sigD);
                const float wD = TDx - TDx*qD; TDx *= qD;
                iD0 = fmaf(wD, sigmoid_f(oB.y), iD0);
                iD1 = fmaf(wD, sigmoid_f(oB.z), iD1);
                iD2 = fmaf(wD, sigmoid_f(oB.w), iD2);
                dDc = fmaf(wD, z01, dDc); wsD += wD;
            }
        }
    }

    // ---- combine the 8 waves' segment states (comb aliases smem) ----
    __syncthreads();
    *(f32x4*)&comb[lane*CSTR + seg*12 + 0] = (f32x4){iA0, iA1, iA2, dAc};
    *(f32x4*)&comb[lane*CSTR + seg*12 + 4] = (f32x4){wsA, TAx, iD0, iD1};
    *(f32x4*)&comb[lane*CSTR + seg*12 + 8] = (f32x4){iD2, dDc, wsD, TDx};
    __syncthreads();

    if (seg == 0) {
        float tA = TAx, tD = TDx;
#pragma unroll
        for (int s = 1; s < 8; ++s) {
            const f32x4 v0 = *(const f32x4*)&comb[lane*CSTR + s*12 + 0];
            const f32x4 v1 = *(const f32x4*)&comb[lane*CSTR + s*12 + 4];
            const f32x4 v2 = *(const f32x4*)&comb[lane*CSTR + s*12 + 8];
            iA0 = fmaf(tA, v0.x, iA0);
            iA1 = fmaf(tA, v0.y, iA1);
            iA2 = fmaf(tA, v0.z, iA2);
            dAc = fmaf(tA, v0.w, dAc);
            wsA = fmaf(tA, v1.x, wsA);
            tA *= v1.y;
            iD0 = fmaf(tD, v1.z, iD0);
            iD1 = fmaf(tD, v1.w, iD1);
            iD2 = fmaf(tD, v2.x, iD2);
            dDc = fmaf(tD, v2.y, dDc);
            wsD = fmaf(tD, v2.z, wsD);
            tD *= v2.w;
        }
        if (ray < N) {
            const float bgA = 1.f - wsA;
            const float bgD = 1.f - wsD;
            float* o = out + (size_t)ray * 9;
            o[0] = iA0 + bgA;
            o[1] = iA1 + bgA;
            o[2] = iA2 + bgA;
            o[3] = dAc;
            o[4] = wsA;
            o[5] = iD0 + bgD;
            o[6] = iD1 + bgD;
            o[7] = iD2 + bgD;
            o[8] = dDc;
        }
    }
}

extern "C" void kernel_launch(void* const* d_in, const int* in_sizes, int n_in,
                              void* d_out, int out_size, void* d_ws, size_t ws_size,
                              hipStream_t stream) {
    const float* rays_o = (const float*)d_in[0];
    const float* rays_d = (const float*)d_in[1];
    const float* W1     = (const float*)d_in[2];
    const float* b1     = (const float*)d_in[3];
    const float* Wsig   = (const float*)d_in[4];
    const float* Wsig_d = (const float*)d_in[5];
    const float* Wc1    = (const float*)d_in[6];
    const float* bc1    = (const float*)d_in[7];
    const float* Wc2    = (const float*)d_in[8];
    const float* Wc2_d  = (const float*)d_in[9];
    const int* num_steps = (const int*)d_in[10];

    const int N = in_sizes[0] / 3;
    float* out = (float*)d_out;
    u32*   ws  = (u32*)d_ws;    // 6 KB used

    hipLaunchKernelGGL(nerf_prep_kernel, dim3(1), dim3(256), 0, stream,
                       W1, b1, Wsig, Wsig_d, Wc1, bc1, Wc2, Wc2_d, ws);

    const int blocks = (N + 63) / 64;   // 64 rays per block (8 waves)
    hipLaunchKernelGGL(nerf_render_kernel, dim3(blocks), dim3(512), 0, stream,
                       rays_o, rays_d, ws, num_steps, out, N);
}